// Round 3
// baseline (153.861 us; speedup 1.0000x reference)
//
#include <hip/hip_runtime.h>

namespace {
constexpr int S = 1024, I = 512, C = 8, H = 8;
constexpr float LNEPS = 1e-5f;
constexpr float SCALE = 0.35355339059327373f; // 8^-0.5
constexpr int CH = 256;                       // s-chunks for partial sums
}

__device__ __forceinline__ float dot8(const float x[8], float4 a, float4 b) {
    float r = x[0] * a.x;
    r += x[1] * a.y; r += x[2] * a.z; r += x[3] * a.w;
    r += x[4] * b.x; r += x[5] * b.y; r += x[6] * b.z; r += x[7] * b.w;
    return r;
}

__device__ __forceinline__ void ln8(float4 a, float4 b, const float gm[8],
                                    const float bt[8], float x[8]) {
    x[0] = a.x; x[1] = a.y; x[2] = a.z; x[3] = a.w;
    x[4] = b.x; x[5] = b.y; x[6] = b.z; x[7] = b.w;
    float mu = 0.f;
#pragma unroll
    for (int c = 0; c < 8; c++) mu += x[c];
    mu *= 0.125f;
    float var = 0.f;
#pragma unroll
    for (int c = 0; c < 8; c++) { float d = x[c] - mu; var += d * d; }
    var *= 0.125f;
    float inv = rsqrtf(var + LNEPS);
#pragma unroll
    for (int c = 0; c < 8; c++) x[c] = (x[c] - mu) * inv * gm[c] + bt[c];
}

// A1: part1[sc][i][c] = sum of LN(m[s,i,:]) over the sc-th s-chunk
__global__ __launch_bounds__(256) void kA1_part(const float* __restrict__ m,
                                                const float* __restrict__ gamma,
                                                const float* __restrict__ beta,
                                                float* __restrict__ part1) {
    int g = blockIdx.x * 256 + threadIdx.x;   // I*CH threads
    int i = g & (I - 1);
    int sc = g >> 9;
    constexpr int NIT = S / CH;
    float gm[8], bt[8];
#pragma unroll
    for (int c = 0; c < 8; c++) { gm[c] = gamma[c]; bt[c] = beta[c]; }
    float acc[8];
#pragma unroll
    for (int c = 0; c < 8; c++) acc[c] = 0.f;
    const float4* m4 = (const float4*)m;
#pragma unroll
    for (int j = 0; j < NIT; j++) {
        int row = (sc * NIT + j) * I + i;
        float x[8];
        ln8(m4[row * 2], m4[row * 2 + 1], gm, bt, x);
#pragma unroll
        for (int c = 0; c < 8; c++) acc[c] += x[c];
    }
    float4* p4 = (float4*)&part1[((size_t)sc * I + i) * 8];
    p4[0] = make_float4(acc[0], acc[1], acc[2], acc[3]);
    p4[1] = make_float4(acc[4], acc[5], acc[6], acc[7]);
}

// A2: reduce part1 over sc for 8 i's per block, then qk[i,h,c2].
// qk[i,h,c2] = SCALE/S * sum_c (xbar[i].Wq_row(h,c)) * Wk[c,c2]
__global__ __launch_bounds__(256) void kA2_qk(const float* __restrict__ part1,
                                              const float* __restrict__ Wq,
                                              const float* __restrict__ Wk,
                                              float* __restrict__ qk) {
    __shared__ float red[4][64];
    __shared__ float xb[64];     // [il][c]
    __shared__ float sWq[512];
    __shared__ float sWk[64];
    int t = threadIdx.x;
    int i0 = blockIdx.x * 8;
    int w = t >> 6, l = t & 63;

    sWq[t] = Wq[t];
    sWq[t + 256] = Wq[t + 256];
    if (t < 64) sWk[t] = Wk[t];

    float sum = 0.f;
    // lane l <-> (il = l>>3, c = l&7); coalesced 256B per wave-iter
    for (int sc = w; sc < CH; sc += 4)
        sum += part1[((size_t)sc * I + i0) * 8 + l];
    red[w][l] = sum;
    __syncthreads();
    if (t < 64) xb[t] = red[0][t] + red[1][t] + red[2][t] + red[3][t];
    __syncthreads();

#pragma unroll
    for (int o = t; o < 512; o += 256) {
        int il = o >> 6, hc2 = o & 63, h = hc2 >> 3, c2 = hc2 & 7;
        float acc = 0.f;
#pragma unroll
        for (int c = 0; c < 8; c++) {
            float q = 0.f;
#pragma unroll
            for (int c3 = 0; c3 < 8; c3++)
                q += xb[il * 8 + c3] * sWq[(h * 8 + c) * 8 + c3];
            acc += q * sWk[c * 8 + c2];
        }
        qk[(i0 + il) * 64 + hc2] = acc * (SCALE / (float)S);
    }
}

// B1: part2[sc][i][h] = sum over sc-th s-chunk of exp(qk[i,h,:].x)
__global__ __launch_bounds__(256, 4) void kB1_part(const float* __restrict__ m,
                                                   const float* __restrict__ gamma,
                                                   const float* __restrict__ beta,
                                                   const float* __restrict__ qk,
                                                   float* __restrict__ part2) {
    int g = blockIdx.x * 256 + threadIdx.x;   // I*CH threads
    int i = g & (I - 1);
    int sc = g >> 9;
    constexpr int NIT = S / CH;
    float gm[8], bt[8];
#pragma unroll
    for (int c = 0; c < 8; c++) { gm[c] = gamma[c]; bt[c] = beta[c]; }
    const float4* qk4 = (const float4*)qk;
    float4 qv[16];
#pragma unroll
    for (int j = 0; j < 16; j++) qv[j] = qk4[i * 16 + j];
    float acc[8];
#pragma unroll
    for (int h = 0; h < 8; h++) acc[h] = 0.f;
    const float4* m4 = (const float4*)m;
#pragma unroll
    for (int j = 0; j < NIT; j++) {
        int row = (sc * NIT + j) * I + i;
        float x[8];
        ln8(m4[row * 2], m4[row * 2 + 1], gm, bt, x);
#pragma unroll
        for (int h = 0; h < 8; h++)
            acc[h] += __expf(dot8(x, qv[h * 2], qv[h * 2 + 1]));
    }
    float4* p4 = (float4*)&part2[((size_t)sc * I + i) * 8];
    p4[0] = make_float4(acc[0], acc[1], acc[2], acc[3]);
    p4[1] = make_float4(acc[4], acc[5], acc[6], acc[7]);
}

// B2: reduce part2 over sc -> rden[i,h] = 1/denom, 8 i's per block
__global__ __launch_bounds__(256) void kB2_rden(const float* __restrict__ part2,
                                                float* __restrict__ rden) {
    __shared__ float red[4][64];
    int t = threadIdx.x;
    int i0 = blockIdx.x * 8;
    int w = t >> 6, l = t & 63;
    float sum = 0.f;
    for (int sc = w; sc < CH; sc += 4)
        sum += part2[((size_t)sc * I + i0) * 8 + l];
    red[w][l] = sum;
    __syncthreads();
    if (t < 64)
        rden[i0 * 8 + t] = 1.0f / (red[0][t] + red[1][t] + red[2][t] + red[3][t]);
}

// C: final output. 2 rows (same i) per thread; weights LDS-resident.
__global__ __launch_bounds__(256, 4) void kC_out(const float* __restrict__ m,
                                                 const float* __restrict__ gamma,
                                                 const float* __restrict__ beta,
                                                 const float* __restrict__ Wv,
                                                 const float* __restrict__ Wg,
                                                 const float* __restrict__ Wo,
                                                 const float* __restrict__ bo,
                                                 const float* __restrict__ qk,
                                                 const float* __restrict__ rden,
                                                 float* __restrict__ out) {
    __shared__ __align__(16) float sWv[64];
    __shared__ __align__(16) float sWg[512];
    __shared__ __align__(16) float sWoT[512];  // sWoT[j][c2] = Wo[c2][j]
    int t = threadIdx.x;
    if (t < 64) sWv[t] = Wv[t];
    sWg[t] = Wg[t];
    sWg[t + 256] = Wg[t + 256];
    {
        int j = t & 63, c2 = t >> 6;
        sWoT[j * 8 + c2] = Wo[c2 * 64 + j];
        sWoT[j * 8 + c2 + 4] = Wo[(c2 + 4) * 64 + j];
    }
    __syncthreads();

    float gm[8], bt[8], bov[8];
#pragma unroll
    for (int c = 0; c < 8; c++) { gm[c] = gamma[c]; bt[c] = beta[c]; bov[c] = bo[c]; }

    int g = blockIdx.x * 256 + t;   // I*(S/2) threads
    int i = g & (I - 1);
    int sg = g >> 9;                // [0,512)
    const float4* m4 = (const float4*)m;
    float4* out4 = (float4*)out;

    float4 xa[2], xb4[2];
#pragma unroll
    for (int r = 0; r < 2; r++) {
        int row = (sg + 512 * r) * I + i;
        xa[r] = m4[row * 2]; xb4[r] = m4[row * 2 + 1];
    }
    float x[2][8];
#pragma unroll
    for (int r = 0; r < 2; r++) ln8(xa[r], xb4[r], gm, bt, x[r]);

    const float4* sWv4 = (const float4*)sWv;
    const float4* sWg4 = (const float4*)sWg;
    const float4* sWoT4 = (const float4*)sWoT;

    float v[2][8];
#pragma unroll
    for (int c = 0; c < 8; c++) {
        float4 w0 = sWv4[c * 2], w1 = sWv4[c * 2 + 1];
#pragma unroll
        for (int r = 0; r < 2; r++) v[r][c] = dot8(x[r], w0, w1);
    }

    float oacc[2][8];
#pragma unroll
    for (int r = 0; r < 2; r++)
#pragma unroll
        for (int c2 = 0; c2 < 8; c2++) oacc[r][c2] = bov[c2];

    const float4* qk4 = (const float4*)qk;
#pragma unroll 1
    for (int h = 0; h < 8; h++) {
        float4 q0 = qk4[i * 16 + h * 2], q1 = qk4[i * 16 + h * 2 + 1];
        float rd = rden[i * 8 + h];
        float a_[2];
#pragma unroll
        for (int r = 0; r < 2; r++) a_[r] = __expf(dot8(x[r], q0, q1)) * rd;
#pragma unroll
        for (int c = 0; c < 8; c++) {
            int hc = h * 8 + c;
            float4 wg0 = sWg4[hc * 2], wg1 = sWg4[hc * 2 + 1];
            float o_[2];
#pragma unroll
            for (int r = 0; r < 2; r++) {
                float z = dot8(x[r], wg0, wg1);
                float gate = __builtin_amdgcn_rcpf(1.0f + __expf(-z));
                o_[r] = gate * a_[r] * v[r][c];
            }
            float4 wo0 = sWoT4[hc * 2], wo1 = sWoT4[hc * 2 + 1];
#pragma unroll
            for (int r = 0; r < 2; r++) {
                oacc[r][0] += o_[r] * wo0.x; oacc[r][1] += o_[r] * wo0.y;
                oacc[r][2] += o_[r] * wo0.z; oacc[r][3] += o_[r] * wo0.w;
                oacc[r][4] += o_[r] * wo1.x; oacc[r][5] += o_[r] * wo1.y;
                oacc[r][6] += o_[r] * wo1.z; oacc[r][7] += o_[r] * wo1.w;
            }
        }
    }
#pragma unroll
    for (int r = 0; r < 2; r++) {
        int row = (sg + 512 * r) * I + i;
        out4[row * 2] = make_float4(oacc[r][0], oacc[r][1], oacc[r][2], oacc[r][3]);
        out4[row * 2 + 1] = make_float4(oacc[r][4], oacc[r][5], oacc[r][6], oacc[r][7]);
    }
}

extern "C" void kernel_launch(void* const* d_in, const int* in_sizes, int n_in,
                              void* d_out, int out_size, void* d_ws, size_t ws_size,
                              hipStream_t stream) {
    const float* m     = (const float*)d_in[0];
    const float* gamma = (const float*)d_in[1];
    const float* beta  = (const float*)d_in[2];
    const float* Wq    = (const float*)d_in[3];
    const float* Wk    = (const float*)d_in[4];
    const float* Wv    = (const float*)d_in[5];
    const float* Wg    = (const float*)d_in[6];
    const float* Wo    = (const float*)d_in[7];
    const float* bo    = (const float*)d_in[8];
    float* out = (float*)d_out;

    float* ws    = (float*)d_ws;
    float* part1 = ws;                              // CH*I*C = 1M floats (4MB)
    float* part2 = part1 + (size_t)CH * I * C;      // 4MB
    float* qk    = part2 + (size_t)CH * I * C;      // I*64
    float* rden  = qk + (size_t)I * 64;             // I*8

    kA1_part<<<I * CH / 256, 256, 0, stream>>>(m, gamma, beta, part1);
    kA2_qk<<<I / 8, 256, 0, stream>>>(part1, Wq, Wk, qk);
    kB1_part<<<I * CH / 256, 256, 0, stream>>>(m, gamma, beta, qk, part2);
    kB2_rden<<<I / 8, 256, 0, stream>>>(part2, rden);
    kC_out<<<I * (S / 2) / 256, 256, 0, stream>>>(m, gamma, beta, Wv, Wg, Wo, bo,
                                                  qk, rden, out);
}